// Round 1
// baseline (319.895 us; speedup 1.0000x reference)
//
#include <hip/hip_runtime.h>

#define N_  16384
#define D_  128
#define M1_ 64
#define K_  8
#define LOG2E 1.44269504088896f

typedef short short8 __attribute__((ext_vector_type(8)));
typedef float f32x4  __attribute__((ext_vector_type(4)));

// pack two f32 -> one dword of 2x bf16 (RNE), gfx950 has no builtin (T12 recipe)
__device__ __forceinline__ unsigned cvt_pk_bf16(float lo, float hi) {
    unsigned r;
    asm("v_cvt_pk_bf16_f32 %0, %1, %2" : "=v"(r) : "v"(lo), "v"(hi));
    return r;
}

// ---- single fused kernel: no prep pass, no workspace ----
// grid (32 nblk, 128 j), 256 thr. Same fragment layouts as the verified
// two-kernel version:
//   A (W): lane(col,quad) frag[mt][ks] elem e = W[j][mt*16+col][ks*32+quad*8+e]
//   B (x): lane(col,quad)          elem e = x[n16*16+col][ks*32+quad*8+e]
//   C rows: m = mt*16 + quad*4 + r
__global__ __launch_bounds__(256) void fused_all(
    const float* __restrict__ x,
    const float* __restrict__ w1p, const float* __restrict__ b1p,
    const float* __restrict__ w1n, const float* __restrict__ b1n,
    const float* __restrict__ w2,  const float* __restrict__ b2,
    const float* __restrict__ w3,  float* __restrict__ out)
{
    const int tid  = threadIdx.x;
    const int wave = tid >> 6, lane = tid & 63;
    const int quad = lane >> 4, col = lane & 15;
    const int j    = blockIdx.y;
    const int nblk = blockIdx.x;                       // fast dim -> XCD = nblk%8

    // ---- A-operand: W fragments in-register from f32 (mask d==j, *LOG2E, cvt) ----
    short8 wfrag[4][4];
    {
        const float* wp = w1p + ((size_t)j * M1_ + col) * D_ + quad * 8;
        const float* wn = w1n + ((size_t)j * M1_ + col) * D_ + quad * 8;
        #pragma unroll
        for (int mt = 0; mt < 4; mt++) {
            #pragma unroll
            for (int ks = 0; ks < 4; ks++) {
                const size_t o = (size_t)mt * 16 * D_ + ks * 32;
                float4 p0 = *(const float4*)(wp + o);
                float4 p1 = *(const float4*)(wp + o + 4);
                float4 n0 = *(const float4*)(wn + o);
                float4 n1 = *(const float4*)(wn + o + 4);
                float f[8];
                f[0] = p0.x - n0.x; f[1] = p0.y - n0.y;
                f[2] = p0.z - n0.z; f[3] = p0.w - n0.w;
                f[4] = p1.x - n1.x; f[5] = p1.y - n1.y;
                f[6] = p1.z - n1.z; f[7] = p1.w - n1.w;
                const int dbase = ks * 32 + quad * 8;
                #pragma unroll
                for (int e = 0; e < 8; e++)
                    f[e] = (dbase + e == j) ? 0.f : f[e] * LOG2E;
                union { unsigned u[4]; short8 s; } r;
                r.u[0] = cvt_pk_bf16(f[0], f[1]);
                r.u[1] = cvt_pk_bf16(f[2], f[3]);
                r.u[2] = cvt_pk_bf16(f[4], f[5]);
                r.u[3] = cvt_pk_bf16(f[6], f[7]);
                wfrag[mt][ks] = r.s;
            }
        }
    }

    // ---- epilogue constants: v[m] = w3[j,:]·w2[:,m], bias, c_j ----
    float w3v[K_];
    #pragma unroll
    for (int k = 0; k < K_; k++) w3v[k] = w3[j * K_ + k];   // j uniform -> s_loads

    f32x4 bias4[4], vm4[4];
    #pragma unroll
    for (int mt = 0; mt < 4; mt++) {
        #pragma unroll
        for (int r = 0; r < 4; r++) {
            const int m = mt * 16 + quad * 4 + r;
            float v = 0.f;
            #pragma unroll
            for (int k = 0; k < K_; k++) v = fmaf(w3v[k], w2[k * M1_ + m], v);
            vm4[mt][r]   = v;
            bias4[mt][r] = (b1p[j * M1_ + m] - b1n[j * M1_ + m]) * LOG2E;
        }
    }
    float cj = 0.f;
    #pragma unroll
    for (int k = 0; k < K_; k++) cj = fmaf(w3v[k], b2[k], cj);

    // ---- B-operand: x loaded directly as f32, cvt_pk'd per subtile ----
    // st row group: n16 = nblk*32 + wave + st*4; per-XCD x slice ~1 MB -> L2-hit
    const float* xg = x + ((size_t)((nblk * 32 + wave) * 16 + col)) * D_ + quad * 8;
    float* outp = out + (size_t)(nblk * 512 + wave * 16 + col) * D_ + j;

    float4 raw[8];                                     // single-buffer prefetch
    #pragma unroll
    for (int ks = 0; ks < 4; ks++) {
        raw[2 * ks]     = *(const float4*)(xg + ks * 32);
        raw[2 * ks + 1] = *(const float4*)(xg + ks * 32 + 4);
    }

    float pr[8];

    #pragma unroll
    for (int st = 0; st < 8; st++) {
        // convert current subtile (waits on loads issued one iteration ago)
        short8 abuf[4];
        #pragma unroll
        for (int ks = 0; ks < 4; ks++) {
            union { unsigned u[4]; short8 s; } r;
            r.u[0] = cvt_pk_bf16(raw[2 * ks].x,     raw[2 * ks].y);
            r.u[1] = cvt_pk_bf16(raw[2 * ks].z,     raw[2 * ks].w);
            r.u[2] = cvt_pk_bf16(raw[2 * ks + 1].x, raw[2 * ks + 1].y);
            r.u[3] = cvt_pk_bf16(raw[2 * ks + 1].z, raw[2 * ks + 1].w);
            abuf[ks] = r.s;
        }

        // issue next subtile's loads; they fly under MFMA + epilogue (~600 cyc)
        if (st < 7) {
            const float* xn = xg + (size_t)(st + 1) * (4 * 16 * D_);
            #pragma unroll
            for (int ks = 0; ks < 4; ks++) {
                raw[2 * ks]     = *(const float4*)(xn + ks * 32);
                raw[2 * ks + 1] = *(const float4*)(xn + ks * 32 + 4);
            }
        }

        f32x4 acc[4];
        #pragma unroll
        for (int mt = 0; mt < 4; mt++) acc[mt] = bias4[mt];   // bias as C-init
        #pragma unroll
        for (int ks = 0; ks < 4; ks++)
            #pragma unroll
            for (int mt = 0; mt < 4; mt++)
                acc[mt] = __builtin_amdgcn_mfma_f32_16x16x32_bf16(
                              wfrag[mt][ks], abuf[ks], acc[mt], 0, 0, 0);

        // epilogue: sigma = 1/(1+2^-t); 4-way combined reciprocal per mt
        // (trans ops per 4 elems: 8 -> 5; products bounded ~2^80, no overflow)
        float partial = 0.f;
        #pragma unroll
        for (int mt = 0; mt < 4; mt++) {
            float e0 = __builtin_amdgcn_exp2f(-acc[mt][0]);
            float e1 = __builtin_amdgcn_exp2f(-acc[mt][1]);
            float e2 = __builtin_amdgcn_exp2f(-acc[mt][2]);
            float e3 = __builtin_amdgcn_exp2f(-acc[mt][3]);
            float u0 = 1.f + e0, u1 = 1.f + e1, u2 = 1.f + e2, u3 = 1.f + e3;
            float p01 = u0 * u1, p23 = u2 * u3;
            float rc  = __builtin_amdgcn_rcpf(p01 * p23);
            partial = fmaf(vm4[mt][0], rc * (p23 * u1), partial);
            partial = fmaf(vm4[mt][1], rc * (p23 * u0), partial);
            partial = fmaf(vm4[mt][2], rc * (p01 * u3), partial);
            partial = fmaf(vm4[mt][3], rc * (p01 * u2), partial);
        }
        pr[st] = partial;                               // no shuffles/stores in loop
    }

    // tail: cross-quad reduction (m-groups live in quads), then 8 stores
    #pragma unroll
    for (int st = 0; st < 8; st++) pr[st] += __shfl_xor(pr[st], 16);
    #pragma unroll
    for (int st = 0; st < 8; st++) pr[st] += __shfl_xor(pr[st], 32);
    if (quad == 0) {
        #pragma unroll
        for (int st = 0; st < 8; st++)
            outp[(size_t)st * 64 * D_] = pr[st] + cj;
    }
}

extern "C" void kernel_launch(void* const* d_in, const int* in_sizes, int n_in,
                              void* d_out, int out_size, void* d_ws, size_t ws_size,
                              hipStream_t stream) {
    (void)in_sizes; (void)n_in; (void)out_size; (void)d_ws; (void)ws_size;
    fused_all<<<dim3(32, 128), 256, 0, stream>>>(
        (const float*)d_in[0],
        (const float*)d_in[1], (const float*)d_in[2],
        (const float*)d_in[3], (const float*)d_in[4],
        (const float*)d_in[5], (const float*)d_in[6],
        (const float*)d_in[7], (float*)d_out);
}

// Round 2
// 124.314 us; speedup vs baseline: 2.5733x; 2.5733x over previous
//
#include <hip/hip_runtime.h>

#define N_  16384
#define D_  128
#define M1_ 64
#define K_  8
#define LOG2E 1.44269504088896f

typedef short short8 __attribute__((ext_vector_type(8)));
typedef float f32x4  __attribute__((ext_vector_type(4)));

// pack two f32 -> one dword of 2x bf16 (RNE); no builtin on gfx950
__device__ __forceinline__ unsigned cvt_pk_bf16(float lo, float hi) {
    unsigned r;
    asm("v_cvt_pk_bf16_f32 %0, %1, %2" : "=v"(r) : "v"(lo), "v"(hi));
    return r;
}

// ---- prep: GATHER version — each thread owns one contiguous 16-B output slot.
// Stores are perfectly coalesced (1 KB/wave); the scattered side is the READS
// (L2/L3-resident, ~16 txns/instr, pipelined). Layouts identical to verified:
//   xbf slot g=(n16*256+ks*64+lane): holds x[n16*16+(lane&15)][ks*32+(lane>>4)*8+e], e=0..7
//   wbf slot g=(j*1024+(ks*4+mt)*64+lane): holds Wmask*LOG2E at
//       [j][m=mt*16+(lane&15)][d=ks*32+(lane>>4)*8+e]
// grid: [0,1024) x | [1024,1536) W | [1536,1568) b/v/c
__global__ void prep_all(const float* __restrict__ x,
                         const float* __restrict__ w1p, const float* __restrict__ b1p,
                         const float* __restrict__ w1n, const float* __restrict__ b1n,
                         const float* __restrict__ w2,  const float* __restrict__ b2,
                         const float* __restrict__ w3,
                         ushort* __restrict__ xbf, ushort* __restrict__ wbf,
                         float* __restrict__ bp, float* __restrict__ vv,
                         float* __restrict__ cv) {
    int bx = blockIdx.x;
    if (bx < 1024) {                                   // x cast+swizzle (gather)
        int g    = bx * 256 + threadIdx.x;             // slot id, 8 ushorts each
        int lane = g & 63;
        int ks   = (g >> 6) & 3;
        int n16  = g >> 8;
        int row   = n16 * 16 + (lane & 15);
        int dbase = ks * 32 + (lane >> 4) * 8;
        const float* xp = x + (size_t)row * D_ + dbase;
        float4 a = *(const float4*)xp;
        float4 b = *(const float4*)(xp + 4);
        union { unsigned u[4]; short8 s; } r;
        r.u[0] = cvt_pk_bf16(a.x, a.y);
        r.u[1] = cvt_pk_bf16(a.z, a.w);
        r.u[2] = cvt_pk_bf16(b.x, b.y);
        r.u[3] = cvt_pk_bf16(b.z, b.w);
        *(short8*)&xbf[(size_t)g * 8] = r.s;           // 16 B coalesced store
    } else if (bx < 1536) {                            // W mask+scale+cast+swizzle
        int g    = (bx - 1024) * 256 + threadIdx.x;
        int lane = g & 63;
        int t    = (g >> 6) & 15;                      // t = ks*4+mt
        int j    = g >> 10;
        int ks = t >> 2, mt = t & 3;
        int m     = mt * 16 + (lane & 15);
        int dbase = ks * 32 + (lane >> 4) * 8;
        const float* pp = w1p + ((size_t)(j * M1_ + m)) * D_ + dbase;
        const float* np = w1n + ((size_t)(j * M1_ + m)) * D_ + dbase;
        float4 p0 = *(const float4*)pp;
        float4 p1 = *(const float4*)(pp + 4);
        float4 n0 = *(const float4*)np;
        float4 n1 = *(const float4*)(np + 4);
        float f[8];
        f[0] = (p0.x - n0.x) * LOG2E; f[1] = (p0.y - n0.y) * LOG2E;
        f[2] = (p0.z - n0.z) * LOG2E; f[3] = (p0.w - n0.w) * LOG2E;
        f[4] = (p1.x - n1.x) * LOG2E; f[5] = (p1.y - n1.y) * LOG2E;
        f[6] = (p1.z - n1.z) * LOG2E; f[7] = (p1.w - n1.w) * LOG2E;
        #pragma unroll
        for (int e = 0; e < 8; e++)
            if (dbase + e == j) f[e] = 0.f;
        union { unsigned u[4]; short8 s; } r;
        r.u[0] = cvt_pk_bf16(f[0], f[1]);
        r.u[1] = cvt_pk_bf16(f[2], f[3]);
        r.u[2] = cvt_pk_bf16(f[4], f[5]);
        r.u[3] = cvt_pk_bf16(f[6], f[7]);
        *(short8*)&wbf[(size_t)g * 8] = r.s;           // 16 B coalesced store
    } else {                                           // b/v/c fold (f32)
        int idx = (bx - 1536) * 256 + threadIdx.x;     // idx < D_*M1_
        int j = idx >> 6, m = idx & 63;
        float v = 0.f;
        for (int k = 0; k < K_; k++) v += w3[j * K_ + k] * w2[k * M1_ + m];
        vv[idx] = v;
        bp[idx] = (b1p[idx] - b1n[idx]) * LOG2E;       // log2e-scaled bias (C-init)
        if (m == 0) {
            float c = 0.f;
            for (int k = 0; k < K_; k++) c += w3[j * K_ + k] * b2[k];
            cv[j] = c;
        }
    }
}

// ---- main: UNCHANGED from the verified 52-us kernel ----
__global__ __launch_bounds__(256) void main_mfma(
    const ushort* __restrict__ xbf, const ushort* __restrict__ wbf,
    const float* __restrict__ bvec, const float* __restrict__ vvec,
    const float* __restrict__ cvec, float* __restrict__ out) {
    const int tid  = threadIdx.x;
    const int wave = tid >> 6, lane = tid & 63;
    const int quad = lane >> 4, col = lane & 15;
    const int j    = blockIdx.y;
    const int nblk = blockIdx.x;                       // fast dim -> XCD = nblk%8

    // W fragments (A operand): one coalesced 16B/lane load each
    short8 wfrag[4][4];                                // [mt][ks]
    const ushort* wg = wbf + (size_t)j * 8192 + lane * 8;
    #pragma unroll
    for (int ks = 0; ks < 4; ks++)
        #pragma unroll
        for (int mt = 0; mt < 4; mt++)
            wfrag[mt][ks] = *(const short8*)&wg[(ks * 4 + mt) * 512];

    // epilogue constants (f32): lane's C-rows are m = mt*16 + quad*4 + r
    f32x4 bias4[4], vm4[4];
    #pragma unroll
    for (int mt = 0; mt < 4; mt++) {
        bias4[mt] = *(const f32x4*)&bvec[j * M1_ + mt * 16 + quad * 4];
        vm4[mt]   = *(const f32x4*)&vvec[j * M1_ + mt * 16 + quad * 4];
    }
    const float cj = cvec[j];

    // x fragments (B operand): n16 = nblk*32 + wave + st*4
    const ushort* xg = xbf + ((size_t)(nblk * 32 + wave)) * 2048 + lane * 8;
    float* outp = out + (size_t)(nblk * 512 + wave * 16 + col) * D_ + j;

    short8 abuf[2][4];
    #pragma unroll
    for (int ks = 0; ks < 4; ks++)
        abuf[0][ks] = *(const short8*)&xg[ks * 512];

    float pr[8];                                       // per-st partial sums

    #pragma unroll
    for (int st = 0; st < 8; st++) {
        const int cur = st & 1, nxt = cur ^ 1;
        if (st < 7) {                                   // prefetch next subtile
            const ushort* xn = xg + (size_t)(st + 1) * 8192;
            #pragma unroll
            for (int ks = 0; ks < 4; ks++)
                abuf[nxt][ks] = *(const short8*)&xn[ks * 512];
        }

        f32x4 acc[4];
        #pragma unroll
        for (int mt = 0; mt < 4; mt++) acc[mt] = bias4[mt];   // bias as C-init
        #pragma unroll
        for (int ks = 0; ks < 4; ks++)
            #pragma unroll
            for (int mt = 0; mt < 4; mt++)
                acc[mt] = __builtin_amdgcn_mfma_f32_16x16x32_bf16(
                              wfrag[mt][ks], abuf[cur][ks], acc[mt], 0, 0, 0);

        // s = 1/(1+2^-t); pr[st] = sum over this lane's 16 m's of v[m]*s
        float partial = 0.f;
        #pragma unroll
        for (int mt = 0; mt < 4; mt++)
            #pragma unroll
            for (int r = 0; r < 4; r++) {
                float e = __builtin_amdgcn_exp2f(-acc[mt][r]);
                float s = __builtin_amdgcn_rcpf(1.0f + e);
                partial = fmaf(s, vm4[mt][r], partial);
            }
        pr[st] = partial;                               // NO shuffles/stores in loop
    }

    // tail: 16 independent cross-quad shuffles (pipelined), then 8 stores
    #pragma unroll
    for (int st = 0; st < 8; st++)
        pr[st] += __shfl_xor(pr[st], 16);
    #pragma unroll
    for (int st = 0; st < 8; st++)
        pr[st] += __shfl_xor(pr[st], 32);
    if (quad == 0) {
        #pragma unroll
        for (int st = 0; st < 8; st++)
            outp[(size_t)st * 64 * D_] = pr[st] + cj;
    }
}

// ---- fp32 fallback (workspace too small) ----
__global__ void fallback_kernel(const float* __restrict__ x,
                                const float* __restrict__ w1p, const float* __restrict__ b1p,
                                const float* __restrict__ w1n, const float* __restrict__ b1n,
                                const float* __restrict__ w2,  const float* __restrict__ b2,
                                const float* __restrict__ w3,  float* __restrict__ out) {
    int n = blockIdx.x, j = blockIdx.y, m = threadIdx.x;
    const float* xr = x + (size_t)n * D_;
    const float* wp = w1p + ((size_t)j * M1_ + m) * D_;
    const float* wn = w1n + ((size_t)j * M1_ + m) * D_;
    float acc = 0.f;
    for (int d = 0; d < D_; d++) {
        if (d == j) continue;
        acc += xr[d] * (wp[d] - wn[d]);
    }
    acc += b1p[j * M1_ + m] - b1n[j * M1_ + m];
    float h = 1.f / (1.f + __expf(-acc));
    float vmv = 0.f;
    for (int k = 0; k < K_; k++) vmv += w3[j * K_ + k] * w2[k * M1_ + m];
    float p = h * vmv;
    for (int off = 1; off < 64; off <<= 1) p += __shfl_xor(p, off);
    if (m == 0) {
        float c = 0.f;
        for (int k = 0; k < K_; k++) c += w3[j * K_ + k] * b2[k];
        out[(size_t)n * D_ + j] = p + c;
    }
}

extern "C" void kernel_launch(void* const* d_in, const int* in_sizes, int n_in,
                              void* d_out, int out_size, void* d_ws, size_t ws_size,
                              hipStream_t stream) {
    const float* x   = (const float*)d_in[0];
    const float* w1p = (const float*)d_in[1];
    const float* b1p = (const float*)d_in[2];
    const float* w1n = (const float*)d_in[3];
    const float* b1n = (const float*)d_in[4];
    const float* w2  = (const float*)d_in[5];
    const float* b2  = (const float*)d_in[6];
    const float* w3  = (const float*)d_in[7];
    float* out = (float*)d_out;

    const size_t off_x = 0;
    const size_t off_w = off_x + (size_t)N_ * D_ * 2;          // x bf16: 4 MB
    const size_t off_b = off_w + (size_t)D_ * M1_ * D_ * 2;    // W bf16: 2 MB
    const size_t off_v = off_b + (size_t)D_ * M1_ * 4;
    const size_t off_c = off_v + (size_t)D_ * M1_ * 4;
    const size_t need  = off_c + (size_t)D_ * 4;

    if (ws_size < need) {
        fallback_kernel<<<dim3(N_, D_), 64, 0, stream>>>(x, w1p, b1p, w1n, b1n, w2, b2, w3, out);
        return;
    }

    ushort* xbf = (ushort*)((char*)d_ws + off_x);
    ushort* wbf = (ushort*)((char*)d_ws + off_w);
    float*  bp  = (float*)((char*)d_ws + off_b);
    float*  vv  = (float*)((char*)d_ws + off_v);
    float*  cv  = (float*)((char*)d_ws + off_c);

    prep_all<<<1568, 256, 0, stream>>>(x, w1p, b1p, w1n, b1n, w2, b2, w3,
                                       xbf, wbf, bp, vv, cv);
    main_mfma<<<dim3(32, 128), 256, 0, stream>>>(xbf, wbf, bp, vv, cv, out);
}